// Round 3
// baseline (811.937 us; speedup 1.0000x reference)
//
#include <hip/hip_runtime.h>

// N=100000 nodes, E=1600000 edges, D=64.
#define D_FEAT 64
#define SCAN_BLOCK 256   // bucket = row >> 8 matches scan blocks

// ---------------- Phase A: per-row edge counts (int atomics) ----------------
__global__ void count_kernel(const int* __restrict__ row, int* __restrict__ counts,
                             int n_edges) {
    int e = blockIdx.x * blockDim.x + threadIdx.x;
    if (e < n_edges) atomicAdd(counts + row[e], 1);
}

// ---------------- Phase B: hierarchical exclusive scan ----------------
// B1: per-block (== per-bucket) sums of counts
__global__ void scan_blocksum_kernel(const int* __restrict__ counts, int* __restrict__ blocksums,
                                     int n) {
    __shared__ int s[SCAN_BLOCK];
    int t = threadIdx.x;
    int i = blockIdx.x * SCAN_BLOCK + t;
    s[t] = (i < n) ? counts[i] : 0;
    __syncthreads();
    for (int o = SCAN_BLOCK / 2; o > 0; o >>= 1) {
        if (t < o) s[t] += s[t + o];
        __syncthreads();
    }
    if (t == 0) blocksums[blockIdx.x] = s[0];
}

// B2: single-block exclusive scan of bucket sums (nb <= 512).
// Writes exclusive bucket offsets back to blocksums AND a cursor copy.
__global__ void scan_top_kernel(int* __restrict__ blocksums, int* __restrict__ bucket_cursor,
                                int* __restrict__ offsets, int nb, int n_nodes) {
    __shared__ int s[512];
    int t = threadIdx.x;
    int v = (t < nb) ? blocksums[t] : 0;
    s[t] = v;
    __syncthreads();
    for (int o = 1; o < 512; o <<= 1) {
        int x = (t >= o) ? s[t - o] : 0;
        __syncthreads();
        s[t] += x;
        __syncthreads();
    }
    if (t < nb) {
        int excl = s[t] - v;
        blocksums[t] = excl;
        bucket_cursor[t] = excl;
    }
    if (t == 0) offsets[n_nodes] = s[511];  // total == n_edges
}

// B3: per-block exclusive scan + block offset -> per-row offsets & cursor
__global__ void scan_final_kernel(const int* __restrict__ counts, const int* __restrict__ blocksums,
                                  int* __restrict__ offsets, int* __restrict__ cursor, int n) {
    __shared__ int s[SCAN_BLOCK];
    int t = threadIdx.x;
    int i = blockIdx.x * SCAN_BLOCK + t;
    int v = (i < n) ? counts[i] : 0;
    s[t] = v;
    __syncthreads();
    for (int o = 1; o < SCAN_BLOCK; o <<= 1) {
        int x = (t >= o) ? s[t - o] : 0;
        __syncthreads();
        s[t] += x;
        __syncthreads();
    }
    if (i < n) {
        int excl = s[t] - v + blocksums[blockIdx.x];
        offsets[i] = excl;
        cursor[i] = excl;
    }
}

// ---------------- Phase C1: partition edges into buckets (dense appends) ----
__global__ void partition_kernel(const int* __restrict__ row, const int* __restrict__ col,
                                 int* __restrict__ bucket_cursor, int2* __restrict__ binned,
                                 int n_edges) {
    int e = blockIdx.x * blockDim.x + threadIdx.x;
    if (e < n_edges) {
        int r = row[e];
        int b = r >> 8;
        int pos = atomicAdd(bucket_cursor + b, 1);
        binned[pos] = make_int2(r, col[e]);
    }
}

// ---------------- Phase C2: L2-local scatter into exact CSR order -----------
// Consecutive i share a bucket -> destinations fall in a ~16KB window.
__global__ void local_scatter_kernel(const int2* __restrict__ binned,
                                     int* __restrict__ cursor, int* __restrict__ sorted_col,
                                     int n_edges) {
    int i = blockIdx.x * blockDim.x + threadIdx.x;
    if (i < n_edges) {
        int2 rc = binned[i];
        int pos = atomicAdd(cursor + rc.x, 1);
        sorted_col[pos] = rc.y;
    }
}

// ---------------- Phase D: one wave per row, 4 edges x float4 gather --------
__global__ void aggregate_kernel(const float* __restrict__ feat,
                                 const int* __restrict__ offsets,
                                 const int* __restrict__ sorted_col,
                                 float* __restrict__ out, int n_nodes) {
    int wave = (blockIdx.x * blockDim.x + threadIdx.x) >> 6;
    int lane = threadIdx.x & 63;
    if (wave >= n_nodes) return;
    int start = offsets[wave];
    int end = offsets[wave + 1];
    int q = lane >> 4;     // which of 4 edges in this group
    int sub = lane & 15;   // which float4 of the 64-dim feature
    float4 acc = make_float4(0.f, 0.f, 0.f, 0.f);
    for (int i = start; i < end; i += 4) {
        int idx = i + q;
        if (idx < end) {
            int c = sorted_col[idx];  // 16 lanes share addr -> broadcast
            float4 v = *reinterpret_cast<const float4*>(feat + (size_t)c * D_FEAT + sub * 4);
            acc.x += v.x; acc.y += v.y; acc.z += v.z; acc.w += v.w;
        }
    }
    // combine the 4 edge-groups: lanes l, l^16, l^32 hold same `sub`
    acc.x += __shfl_xor(acc.x, 16, 64);
    acc.y += __shfl_xor(acc.y, 16, 64);
    acc.z += __shfl_xor(acc.z, 16, 64);
    acc.w += __shfl_xor(acc.w, 16, 64);
    acc.x += __shfl_xor(acc.x, 32, 64);
    acc.y += __shfl_xor(acc.y, 32, 64);
    acc.z += __shfl_xor(acc.z, 32, 64);
    acc.w += __shfl_xor(acc.w, 32, 64);
    if (q == 0) {
        float inv = 1.0f / fmaxf((float)(end - start), 1.0f);
        size_t off = (size_t)wave * D_FEAT + sub * 4;
        float4 f = *reinterpret_cast<const float4*>(feat + off);
        float4 o;
        o.x = f.x + acc.x * inv;
        o.y = f.y + acc.y * inv;
        o.z = f.z + acc.z * inv;
        o.w = f.w + acc.w * inv;
        *reinterpret_cast<float4*>(out + off) = o;
    }
}

extern "C" void kernel_launch(void* const* d_in, const int* in_sizes, int n_in,
                              void* d_out, int out_size, void* d_ws, size_t ws_size,
                              hipStream_t stream) {
    const float* feat = (const float*)d_in[0];
    const int* row = (const int*)d_in[1];
    const int* col = (const int*)d_in[2];
    float* out = (float*)d_out;

    const int n_nodes = in_sizes[0] / D_FEAT;
    const int n_edges = in_sizes[1];
    const int nb = (n_nodes + SCAN_BLOCK - 1) / SCAN_BLOCK;  // 391

    // Workspace layout:
    char* ws = (char*)d_ws;
    size_t p = 0;
    int* counts        = (int*)(ws + p); p += (size_t)n_nodes * 4;
    int* offsets       = (int*)(ws + p); p += (size_t)(n_nodes + 1) * 4;
    int* cursor        = (int*)(ws + p); p += (size_t)n_nodes * 4;
    int* sorted_col    = (int*)(ws + p); p += (size_t)n_edges * 4;
    int* blocksums     = (int*)(ws + p); p += 512 * 4;
    int* bucket_cursor = (int*)(ws + p); p += 512 * 4;
    p = (p + 15) & ~(size_t)15;
    int2* binned       = (int2*)(ws + p); p += (size_t)n_edges * 8;

    hipMemsetAsync(counts, 0, (size_t)n_nodes * 4, stream);

    {
        int block = 256, grid = (n_edges + block - 1) / block;
        count_kernel<<<grid, block, 0, stream>>>(row, counts, n_edges);
    }
    scan_blocksum_kernel<<<nb, SCAN_BLOCK, 0, stream>>>(counts, blocksums, n_nodes);
    scan_top_kernel<<<1, 512, 0, stream>>>(blocksums, bucket_cursor, offsets, nb, n_nodes);
    scan_final_kernel<<<nb, SCAN_BLOCK, 0, stream>>>(counts, blocksums, offsets, cursor, n_nodes);
    {
        int block = 256, grid = (n_edges + block - 1) / block;
        partition_kernel<<<grid, block, 0, stream>>>(row, col, bucket_cursor, binned, n_edges);
    }
    {
        int block = 256, grid = (n_edges + block - 1) / block;
        local_scatter_kernel<<<grid, block, 0, stream>>>(binned, cursor, sorted_col, n_edges);
    }
    {
        long long total = (long long)n_nodes * 64;  // one wave per node
        int block = 256;
        int grid = (int)((total + block - 1) / block);
        aggregate_kernel<<<grid, block, 0, stream>>>(feat, offsets, sorted_col, out, n_nodes);
    }
}